// Round 2
// baseline (12993.767 us; speedup 1.0000x reference)
//
#include <hip/hip_runtime.h>

#define N_BATCH 32768
#define N_IMG   5
#define DIM     512
#define NKERN   200
#define DCAT    600
#define NROWS   (N_BATCH * N_IMG)   // 163840

// ---------------------------------------------------------------------------
// Repack conv weights: w[c][k][d] -> w4T[((k*128 + d4)*200 + c)*4 + j]
// ---------------------------------------------------------------------------
template<int K>
__global__ void transpose_w(const float* __restrict__ w, float* __restrict__ w4T) {
    int g = blockIdx.x * 256 + threadIdx.x;
    if (g >= K * 128 * NKERN) return;
    int k  = g / (128 * NKERN);
    int r  = g - k * (128 * NKERN);
    int d4 = r / NKERN;
    int c  = r - d4 * NKERN;
    float4 v = *(const float4*)(w + (c * K + k) * DIM + d4 * 4);
    ((float4*)w4T)[g] = v;
}

// ---------------------------------------------------------------------------
// Conv block, fp64 accumulation (products of fp32 inputs are EXACT in f64).
// Block: 4 samples (LDS) x 128 channels (2/thread), 256 threads.
// ---------------------------------------------------------------------------
template<int K, int T>
__global__ __launch_bounds__(256) void conv_relu_max(
    const float* __restrict__ feats, const float* __restrict__ w4T,
    const float* __restrict__ bias, float* __restrict__ cout, int conv_off) {
    __shared__ float fsh[4 * 2560];                       // 40 KB
    int tid = threadIdx.x;
    int tx = tid & 63, ty = tid >> 6;
    const float4* fg = (const float4*)(feats + blockIdx.x * (4 * 2560));
    float4* fs4 = (float4*)fsh;
#pragma unroll
    for (int i = 0; i < 10; i++) fs4[i * 256 + tid] = fg[i * 256 + tid];
    __syncthreads();

    int c0 = blockIdx.y * 128 + tx, c1 = c0 + 64;
    int c0c = min(c0, NKERN - 1), c1c = min(c1, NKERN - 1);
    double acc0[T], acc1[T];
#pragma unroll
    for (int t = 0; t < T; t++) { acc0[t] = 0.0; acc1[t] = 0.0; }
    const float4* fr = (const float4*)(fsh + ty * 2560);
    const float4* w4 = (const float4*)w4T;

    for (int k = 0; k < K; k++) {
        for (int d4 = 0; d4 < 128; d4++) {
            float4 w0 = w4[(k * 128 + d4) * NKERN + c0c];
            float4 w1 = w4[(k * 128 + d4) * NKERN + c1c];
            double w0x = w0.x, w0y = w0.y, w0z = w0.z, w0w = w0.w;
            double w1x = w1.x, w1y = w1.y, w1z = w1.z, w1w = w1.w;
#pragma unroll
            for (int t = 0; t < T; t++) {
                float4 f = fr[(t + k) * 128 + d4];
                double fx = f.x, fy = f.y, fz = f.z, fw = f.w;
                acc0[t] += fx * w0x; acc0[t] += fy * w0y;
                acc0[t] += fz * w0z; acc0[t] += fw * w0w;
                acc1[t] += fx * w1x; acc1[t] += fy * w1y;
                acc1[t] += fz * w1z; acc1[t] += fw * w1w;
            }
        }
    }
    int n = blockIdx.x * 4 + ty;
    if (c0 < NKERN) {
        double b = (double)bias[c0], m = acc0[0] + b;
#pragma unroll
        for (int t = 1; t < T; t++) m = fmax(m, acc0[t] + b);
        cout[n * DCAT + conv_off + c0] = (float)fmax(m, 0.0);
    }
    if (c1 < NKERN) {
        double b = (double)bias[c1], m = acc1[0] + b;
#pragma unroll
        for (int t = 1; t < T; t++) m = fmax(m, acc1[t] + b);
        cout[n * DCAT + conv_off + c1] = (float)fmax(m, 0.0);
    }
}

// NOTE: conv output 'c' is rounded to fp32 — this mirrors the np reference only
// if np computes layer-by-layer in f64 from the fp32 'c'... to be safe, keep c
// in fp32? No: np-f64 keeps full precision throughout. Store c as double.
// (See kernel below: cout is written as double via the cout_d pointer variant.)

template<int K, int T>
__global__ __launch_bounds__(256) void conv_relu_max_d(
    const float* __restrict__ feats, const float* __restrict__ w4T,
    const float* __restrict__ bias, double* __restrict__ cout, int conv_off) {
    __shared__ float fsh[4 * 2560];
    int tid = threadIdx.x;
    int tx = tid & 63, ty = tid >> 6;
    const float4* fg = (const float4*)(feats + blockIdx.x * (4 * 2560));
    float4* fs4 = (float4*)fsh;
#pragma unroll
    for (int i = 0; i < 10; i++) fs4[i * 256 + tid] = fg[i * 256 + tid];
    __syncthreads();

    int c0 = blockIdx.y * 128 + tx, c1 = c0 + 64;
    int c0c = min(c0, NKERN - 1), c1c = min(c1, NKERN - 1);
    double acc0[T], acc1[T];
#pragma unroll
    for (int t = 0; t < T; t++) { acc0[t] = 0.0; acc1[t] = 0.0; }
    const float4* fr = (const float4*)(fsh + ty * 2560);
    const float4* w4 = (const float4*)w4T;

    for (int k = 0; k < K; k++) {
        for (int d4 = 0; d4 < 128; d4++) {
            float4 w0 = w4[(k * 128 + d4) * NKERN + c0c];
            float4 w1 = w4[(k * 128 + d4) * NKERN + c1c];
            double w0x = w0.x, w0y = w0.y, w0z = w0.z, w0w = w0.w;
            double w1x = w1.x, w1y = w1.y, w1z = w1.z, w1w = w1.w;
#pragma unroll
            for (int t = 0; t < T; t++) {
                float4 f = fr[(t + k) * 128 + d4];
                double fx = f.x, fy = f.y, fz = f.z, fw = f.w;
                acc0[t] += fx * w0x; acc0[t] += fy * w0y;
                acc0[t] += fz * w0z; acc0[t] += fw * w0w;
                acc1[t] += fx * w1x; acc1[t] += fy * w1y;
                acc1[t] += fz * w1z; acc1[t] += fw * w1w;
            }
        }
    }
    int n = blockIdx.x * 4 + ty;
    if (c0 < NKERN) {
        double b = (double)bias[c0], m = acc0[0] + b;
#pragma unroll
        for (int t = 1; t < T; t++) m = fmax(m, acc0[t] + b);
        cout[n * DCAT + conv_off + c0] = fmax(m, 0.0);
    }
    if (c1 < NKERN) {
        double b = (double)bias[c1], m = acc1[0] + b;
#pragma unroll
        for (int t = 1; t < T; t++) m = fmax(m, acc1[t] + b);
        cout[n * DCAT + conv_off + c1] = fmax(m, 0.0);
    }
}

// ---------------------------------------------------------------------------
// f64 GEMM: C[M,Nc] = act(A[M,Kd] @ B[Kd,Nc] + bias). A is double (from ws),
// B/bias are fp32 params (exact in f64). 64x64 tile, BK=8, 4x4 micro-tile.
// A staged in LDS as double (k-major), B as float.
// ---------------------------------------------------------------------------
template<int RELU>
__global__ __launch_bounds__(256) void gemm_bias_d(
    const double* __restrict__ A, const float* __restrict__ B,
    const float* __restrict__ bias, double* __restrict__ C,
    int Kd, int Nc) {
    __shared__ double AsT[8][66];    // 4224 B rows -> 33 KB? 8*66*8 = 4224*8? no: 8*66*8B = 4224B*? (8 rows * 66 * 8B = 4224B? 66*8=528B/row *8 = 4224B) OK
    __shared__ float  Bs[8][68];
    int tid = threadIdx.x;
    int tx = tid & 15, ty = tid >> 4;
    int m0 = blockIdx.x * 64, n0 = blockIdx.y * 64;
    double acc[4][4] = {};
    int arow = tid >> 2, ak = tid & 3;          // 64 rows x 4 k-pairs
    int br = tid >> 5, bc = tid & 31;           // 8 k x 32 col-pairs

    for (int kk = 0; kk < Kd; kk += 8) {
        int gk = kk + ak * 2;
        double2 ga = make_double2(0.0, 0.0);
        if (gk + 1 < Kd) ga = *(const double2*)(A + (size_t)(m0 + arow) * Kd + gk);
        else if (gk < Kd) ga.x = A[(size_t)(m0 + arow) * Kd + gk];
        AsT[ak * 2 + 0][arow] = ga.x;
        AsT[ak * 2 + 1][arow] = ga.y;
        float2 gb = make_float2(0.f, 0.f);
        int bcol = n0 + bc * 2;
        if (kk + br < Kd && bcol < Nc) gb = *(const float2*)(B + (size_t)(kk + br) * Nc + bcol);
        *(float2*)&Bs[br][bc * 2] = gb;
        __syncthreads();
#pragma unroll
        for (int k2 = 0; k2 < 8; k2++) {
            double a0 = AsT[k2][ty * 4 + 0], a1 = AsT[k2][ty * 4 + 1];
            double a2 = AsT[k2][ty * 4 + 2], a3 = AsT[k2][ty * 4 + 3];
            float4 b4 = *(const float4*)&Bs[k2][tx * 4];
            double b[4] = {(double)b4.x, (double)b4.y, (double)b4.z, (double)b4.w};
            double a[4] = {a0, a1, a2, a3};
#pragma unroll
            for (int i = 0; i < 4; i++)
#pragma unroll
                for (int j = 0; j < 4; j++)
                    acc[i][j] += a[i] * b[j];
        }
        __syncthreads();
    }
    int cb = n0 + tx * 4;
    if (cb < Nc) {
        float4 bs = *(const float4*)(bias + cb);
#pragma unroll
        for (int i = 0; i < 4; i++) {
            size_t row = m0 + ty * 4 + i;
            double v0 = acc[i][0] + (double)bs.x, v1 = acc[i][1] + (double)bs.y;
            double v2 = acc[i][2] + (double)bs.z, v3 = acc[i][3] + (double)bs.w;
            if (RELU) {
                v0 = fmax(v0, 0.0); v1 = fmax(v1, 0.0);
                v2 = fmax(v2, 0.0); v3 = fmax(v3, 0.0);
            }
            double* cp = C + row * Nc + cb;
            cp[0] = v0; cp[1] = v1; cp[2] = v2; cp[3] = v3;
        }
    }
}

// ---------------------------------------------------------------------------
// Fused fc0(+relu)+fcs, f64. A row = [feats(f32), ci(f64)]. 64 rows x 64 cols.
// ---------------------------------------------------------------------------
__global__ __launch_bounds__(256) void fc0_fcs_partial_d(
    const float* __restrict__ feats, const double* __restrict__ ci,
    const float* __restrict__ W, const float* __restrict__ b0,
    const float* __restrict__ fw, double* __restrict__ partial) {
    __shared__ double AsT[8][66];
    __shared__ float  Bs[8][68];
    __shared__ double red[64][17];
    int tid = threadIdx.x;
    int tx = tid & 15, ty = tid >> 4;
    int m0 = blockIdx.x * 64, n0 = blockIdx.y * 64;
    double acc[4][4] = {};
    int arow = tid >> 2, ak = tid & 3;
    int br = tid >> 5, bc = tid & 31;
    int rg = m0 + arow;
    int n = rg / 5, img = rg - n * 5;
    const float*  afeat = feats + (size_t)n * (N_IMG * DIM) + (size_t)img * DIM;
    const double* aci   = ci + (size_t)n * DIM - DIM;   // indexed with gk in [512,1024)

    for (int kk = 0; kk < 2 * DIM; kk += 8) {
        int gk = kk + ak * 2;
        double2 ga;
        if (gk < DIM) {
            float2 gf = *(const float2*)(afeat + gk);
            ga.x = gf.x; ga.y = gf.y;
        } else {
            ga = *(const double2*)(aci + gk);
        }
        AsT[ak * 2 + 0][arow] = ga.x;
        AsT[ak * 2 + 1][arow] = ga.y;
        float2 gb = *(const float2*)(W + (size_t)(kk + br) * DIM + n0 + bc * 2);
        *(float2*)&Bs[br][bc * 2] = gb;
        __syncthreads();
#pragma unroll
        for (int k2 = 0; k2 < 8; k2++) {
            double a[4] = {AsT[k2][ty * 4 + 0], AsT[k2][ty * 4 + 1],
                           AsT[k2][ty * 4 + 2], AsT[k2][ty * 4 + 3]};
            float4 b4 = *(const float4*)&Bs[k2][tx * 4];
            double b[4] = {(double)b4.x, (double)b4.y, (double)b4.z, (double)b4.w};
#pragma unroll
            for (int i = 0; i < 4; i++)
#pragma unroll
                for (int j = 0; j < 4; j++)
                    acc[i][j] += a[i] * b[j];
        }
        __syncthreads();
    }
    int cb = n0 + tx * 4;
    float4 b04 = *(const float4*)(b0 + cb);
    float4 fw4 = *(const float4*)(fw + cb);
#pragma unroll
    for (int i = 0; i < 4; i++) {
        double p = 0.0;
        p += fmax(acc[i][0] + (double)b04.x, 0.0) * (double)fw4.x;
        p += fmax(acc[i][1] + (double)b04.y, 0.0) * (double)fw4.y;
        p += fmax(acc[i][2] + (double)b04.z, 0.0) * (double)fw4.z;
        p += fmax(acc[i][3] + (double)b04.w, 0.0) * (double)fw4.w;
        red[ty * 4 + i][tx] = p;
    }
    __syncthreads();
    if (tid < 64) {
        double s = 0.0;
#pragma unroll
        for (int x = 0; x < 16; x++) s += red[tid][x];
        partial[(size_t)(m0 + tid) * 8 + blockIdx.y] = s;
    }
}

__global__ void score_finish(const double* __restrict__ partial,
                             const float* __restrict__ fcs_b,
                             float* __restrict__ out,
                             double* __restrict__ scored) {
    int m = blockIdx.x * 256 + threadIdx.x;
    if (m >= NROWS) return;
    double s = (double)fcs_b[0];
#pragma unroll
    for (int q = 0; q < 8; q++) s += partial[(size_t)m * 8 + q];
    out[m] = (float)s;
    scored[m] = s;
}

// rank from f64 scores (stable double-argsort of -s)
__global__ void rank_kernel(const double* __restrict__ scored, float* __restrict__ out) {
    int n = blockIdx.x * 256 + threadIdx.x;
    if (n >= N_BATCH) return;
    double s[5];
#pragma unroll
    for (int i = 0; i < 5; i++) s[i] = scored[n * 5 + i];
#pragma unroll
    for (int i = 0; i < 5; i++) {
        int rk = 0;
#pragma unroll
        for (int j = 0; j < 5; j++)
            rk += (s[j] > s[i]) || (s[j] == s[i] && j < i);
        out[NROWS + n * 5 + i] = (float)rk;
    }
}

// ---------------------------------------------------------------------------
// Workspace layout (bytes):
//   c  (double [N,600])   @ 0           : 157,286,400
//   h  (double [N,600])   @ 157,286,400 : 157,286,400   (later reused: partial 10.5MB, scored 1.3MB)
//   ci (double [N,512])   @ 314,572,800 : 134,217,728
//   wT (fp32 repacks)     @ 448,790,528 : 4,096,000
//   total ~453 MB
// ---------------------------------------------------------------------------
extern "C" void kernel_launch(void* const* d_in, const int* in_sizes, int n_in,
                              void* d_out, int out_size, void* d_ws, size_t ws_size,
                              hipStream_t stream) {
    (void)in_sizes; (void)n_in; (void)out_size; (void)ws_size;
    const float* feats = (const float*)d_in[0];
    const float* w2    = (const float*)d_in[1];
    const float* b2    = (const float*)d_in[2];
    const float* w3    = (const float*)d_in[3];
    const float* b3    = (const float*)d_in[4];
    const float* w5    = (const float*)d_in[5];
    const float* b5    = (const float*)d_in[6];
    const float* fc1_w = (const float*)d_in[7];
    const float* fc1_b = (const float*)d_in[8];
    const float* fc2_w = (const float*)d_in[9];
    const float* fc2_b = (const float*)d_in[10];
    const float* fc0_w = (const float*)d_in[11];
    const float* fc0_b = (const float*)d_in[12];
    const float* fcs_w = (const float*)d_in[13];
    const float* fcs_b = (const float*)d_in[14];

    char* ws = (char*)d_ws;
    double* c  = (double*)ws;                                  // [N,600] f64
    double* h  = (double*)(ws + 157286400);                    // [N,600] f64
    double* ci = (double*)(ws + 314572800);                    // [N,512] f64
    float*  wT = (float*)(ws + 448790528);
    float* w2T = wT;                 // 204,800 floats
    float* w3T = wT + 204800;        // 307,200 floats
    float* w5T = wT + 512000;        // 512,000 floats

    transpose_w<2><<<dim3((2 * 128 * NKERN + 255) / 256), 256, 0, stream>>>(w2, w2T);
    transpose_w<3><<<dim3((3 * 128 * NKERN + 255) / 256), 256, 0, stream>>>(w3, w3T);
    transpose_w<5><<<dim3((5 * 128 * NKERN + 255) / 256), 256, 0, stream>>>(w5, w5T);

    conv_relu_max_d<2, 4><<<dim3(N_BATCH / 4, 2), 256, 0, stream>>>(feats, w2T, b2, c, 0);
    conv_relu_max_d<3, 3><<<dim3(N_BATCH / 4, 2), 256, 0, stream>>>(feats, w3T, b3, c, 200);
    conv_relu_max_d<5, 1><<<dim3(N_BATCH / 4, 2), 256, 0, stream>>>(feats, w5T, b5, c, 400);

    gemm_bias_d<1><<<dim3(N_BATCH / 64, 10), 256, 0, stream>>>(c, fc1_w, fc1_b, h, DCAT, DCAT);
    gemm_bias_d<0><<<dim3(N_BATCH / 64, 8), 256, 0, stream>>>(h, fc2_w, fc2_b, ci, DCAT, DIM);

    double* partial = (double*)(ws + 157286400);               // overwrites h (dead)
    fc0_fcs_partial_d<<<dim3(NROWS / 64, 8), 256, 0, stream>>>(feats, ci, fc0_w, fc0_b, fcs_w, partial);

    double* scored = (double*)(ws + 157286400 + 10485760);     // after partial
    float* out = (float*)d_out;
    score_finish<<<dim3((NROWS + 255) / 256), 256, 0, stream>>>(partial, fcs_b, out, scored);
    rank_kernel<<<dim3((N_BATCH + 255) / 256), 256, 0, stream>>>(scored, out);
}

// Round 3
// 12472.086 us; speedup vs baseline: 1.0418x; 1.0418x over previous
//
#include <hip/hip_runtime.h>

#define N_BATCH 32768
#define N_IMG   5
#define DIM     512
#define NKERN   200
#define DCAT    600
#define NROWS   (N_BATCH * N_IMG)   // 163840
#define EPS_FLAG 2e-4f

// ---------------------------------------------------------------------------
// Repack conv weights: w[c][k][d] -> w4T[((k*128 + d4)*200 + c)*4 + j]
// ---------------------------------------------------------------------------
template<int K>
__global__ void transpose_w(const float* __restrict__ w, float* __restrict__ w4T) {
    int g = blockIdx.x * 256 + threadIdx.x;
    if (g >= K * 128 * NKERN) return;
    int k  = g / (128 * NKERN);
    int r  = g - k * (128 * NKERN);
    int d4 = r / NKERN;
    int c  = r - d4 * NKERN;
    float4 v = *(const float4*)(w + (c * K + k) * DIM + d4 * 4);
    ((float4*)w4T)[g] = v;
}

// ---------------------------------------------------------------------------
// fp32 conv block: 4 samples (LDS) x 128 channels (2/thread), 256 threads.
// ---------------------------------------------------------------------------
template<int K, int T>
__global__ __launch_bounds__(256) void conv_relu_max(
    const float* __restrict__ feats, const float* __restrict__ w4T,
    const float* __restrict__ bias, float* __restrict__ cout, int conv_off) {
    __shared__ float fsh[4 * 2560];                       // 40 KB
    int tid = threadIdx.x;
    int tx = tid & 63, ty = tid >> 6;
    const float4* fg = (const float4*)(feats + blockIdx.x * (4 * 2560));
    float4* fs4 = (float4*)fsh;
#pragma unroll
    for (int i = 0; i < 10; i++) fs4[i * 256 + tid] = fg[i * 256 + tid];
    __syncthreads();

    int c0 = blockIdx.y * 128 + tx, c1 = c0 + 64;
    int c0c = min(c0, NKERN - 1), c1c = min(c1, NKERN - 1);
    float acc0[T], acc1[T];
#pragma unroll
    for (int t = 0; t < T; t++) { acc0[t] = 0.f; acc1[t] = 0.f; }
    const float4* fr = (const float4*)(fsh + ty * 2560);
    const float4* w4 = (const float4*)w4T;

    for (int k = 0; k < K; k++) {
#pragma unroll 2
        for (int d4 = 0; d4 < 128; d4++) {
            float4 w0 = w4[(k * 128 + d4) * NKERN + c0c];
            float4 w1 = w4[(k * 128 + d4) * NKERN + c1c];
#pragma unroll
            for (int t = 0; t < T; t++) {
                float4 f = fr[(t + k) * 128 + d4];
                acc0[t] += f.x * w0.x + f.y * w0.y + f.z * w0.z + f.w * w0.w;
                acc1[t] += f.x * w1.x + f.y * w1.y + f.z * w1.z + f.w * w1.w;
            }
        }
    }
    int n = blockIdx.x * 4 + ty;
    if (c0 < NKERN) {
        float b = bias[c0], m = acc0[0] + b;
#pragma unroll
        for (int t = 1; t < T; t++) m = fmaxf(m, acc0[t] + b);
        cout[n * DCAT + conv_off + c0] = fmaxf(m, 0.f);
    }
    if (c1 < NKERN) {
        float b = bias[c1], m = acc1[0] + b;
#pragma unroll
        for (int t = 1; t < T; t++) m = fmaxf(m, acc1[t] + b);
        cout[n * DCAT + conv_off + c1] = fmaxf(m, 0.f);
    }
}

// ---------------------------------------------------------------------------
// fp32 GEMM: C = act(A@B + bias). 64x64 tile, BK=16, 4x4 micro-tile.
// ---------------------------------------------------------------------------
template<int RELU>
__global__ __launch_bounds__(256) void gemm_bias(
    const float* __restrict__ A, const float* __restrict__ B,
    const float* __restrict__ bias, float* __restrict__ C,
    int Kd, int Nc) {
    __shared__ float AsT[16][68];
    __shared__ float Bs[16][68];
    int tid = threadIdx.x;
    int tx = tid & 15, ty = tid >> 4;
    int m0 = blockIdx.x * 64, n0 = blockIdx.y * 64;
    float acc[4][4] = {};
    int arow = tid >> 2, ac4 = tid & 3;
    int br = tid >> 4, bc = tid & 15;

    for (int kk = 0; kk < Kd; kk += 16) {
        int gk = kk + ac4 * 4;
        float4 ga = make_float4(0.f, 0.f, 0.f, 0.f);
        if (gk < Kd) ga = *(const float4*)(A + (size_t)(m0 + arow) * Kd + gk);
        AsT[ac4 * 4 + 0][arow] = ga.x;
        AsT[ac4 * 4 + 1][arow] = ga.y;
        AsT[ac4 * 4 + 2][arow] = ga.z;
        AsT[ac4 * 4 + 3][arow] = ga.w;
        float4 gb = make_float4(0.f, 0.f, 0.f, 0.f);
        int bcol = n0 + bc * 4;
        if (kk + br < Kd && bcol < Nc) gb = *(const float4*)(B + (size_t)(kk + br) * Nc + bcol);
        *(float4*)&Bs[br][bc * 4] = gb;
        __syncthreads();
#pragma unroll
        for (int k2 = 0; k2 < 16; k2++) {
            float4 a4 = *(const float4*)&AsT[k2][ty * 4];
            float4 b4 = *(const float4*)&Bs[k2][tx * 4];
            float a[4] = {a4.x, a4.y, a4.z, a4.w};
            float b[4] = {b4.x, b4.y, b4.z, b4.w};
#pragma unroll
            for (int i = 0; i < 4; i++)
#pragma unroll
                for (int j = 0; j < 4; j++)
                    acc[i][j] += a[i] * b[j];
        }
        __syncthreads();
    }
    int cb = n0 + tx * 4;
    if (cb < Nc) {
        float4 bs = *(const float4*)(bias + cb);
#pragma unroll
        for (int i = 0; i < 4; i++) {
            size_t row = m0 + ty * 4 + i;
            float4 v;
            v.x = acc[i][0] + bs.x; v.y = acc[i][1] + bs.y;
            v.z = acc[i][2] + bs.z; v.w = acc[i][3] + bs.w;
            if (RELU) {
                v.x = fmaxf(v.x, 0.f); v.y = fmaxf(v.y, 0.f);
                v.z = fmaxf(v.z, 0.f); v.w = fmaxf(v.w, 0.f);
            }
            *(float4*)(C + row * Nc + cb) = v;
        }
    }
}

// ---------------------------------------------------------------------------
// Fused fc0(+relu)+fcs, fp32. 64 rows x 64 cols per block; col-tile partials.
// ---------------------------------------------------------------------------
__global__ __launch_bounds__(256) void fc0_fcs_partial(
    const float* __restrict__ feats, const float* __restrict__ ci,
    const float* __restrict__ W, const float* __restrict__ b0,
    const float* __restrict__ fw, float* __restrict__ partial) {
    __shared__ float AsT[16][68];
    __shared__ float Bs[16][68];
    __shared__ float red[64][17];
    int tid = threadIdx.x;
    int tx = tid & 15, ty = tid >> 4;
    int m0 = blockIdx.x * 64, n0 = blockIdx.y * 64;
    float acc[4][4] = {};
    int arow = tid >> 2, ac4 = tid & 3;
    int br = tid >> 4, bc = tid & 15;
    int rg = m0 + arow;
    int n = rg / 5, img = rg - n * 5;
    const float* afeat = feats + (size_t)n * (N_IMG * DIM) + (size_t)img * DIM;
    const float* aci   = ci + (size_t)n * DIM - DIM;    // indexed with gk in [512,1024)

    for (int kk = 0; kk < 2 * DIM; kk += 16) {
        int gk = kk + ac4 * 4;
        float4 ga = (gk < DIM) ? *(const float4*)(afeat + gk)
                               : *(const float4*)(aci + gk);
        AsT[ac4 * 4 + 0][arow] = ga.x;
        AsT[ac4 * 4 + 1][arow] = ga.y;
        AsT[ac4 * 4 + 2][arow] = ga.z;
        AsT[ac4 * 4 + 3][arow] = ga.w;
        float4 gb = *(const float4*)(W + (size_t)(kk + br) * DIM + n0 + bc * 4);
        *(float4*)&Bs[br][bc * 4] = gb;
        __syncthreads();
#pragma unroll
        for (int k2 = 0; k2 < 16; k2++) {
            float4 a4 = *(const float4*)&AsT[k2][ty * 4];
            float4 b4 = *(const float4*)&Bs[k2][tx * 4];
            float a[4] = {a4.x, a4.y, a4.z, a4.w};
            float b[4] = {b4.x, b4.y, b4.z, b4.w};
#pragma unroll
            for (int i = 0; i < 4; i++)
#pragma unroll
                for (int j = 0; j < 4; j++)
                    acc[i][j] += a[i] * b[j];
        }
        __syncthreads();
    }
    int cb = n0 + tx * 4;
    float4 b04 = *(const float4*)(b0 + cb);
    float4 fw4 = *(const float4*)(fw + cb);
#pragma unroll
    for (int i = 0; i < 4; i++) {
        float p = 0.f;
        p += fmaxf(acc[i][0] + b04.x, 0.f) * fw4.x;
        p += fmaxf(acc[i][1] + b04.y, 0.f) * fw4.y;
        p += fmaxf(acc[i][2] + b04.z, 0.f) * fw4.z;
        p += fmaxf(acc[i][3] + b04.w, 0.f) * fw4.w;
        red[ty * 4 + i][tx] = p;
    }
    __syncthreads();
    if (tid < 64) {
        float s = 0.f;
#pragma unroll
        for (int x = 0; x < 16; x++) s += red[tid][x];
        partial[(size_t)(m0 + tid) * 8 + blockIdx.y] = s;
    }
}

__global__ void score_finish(const float* __restrict__ partial,
                             const float* __restrict__ fcs_b,
                             float* __restrict__ out) {
    int m = blockIdx.x * 256 + threadIdx.x;
    if (m >= NROWS) return;
    float s = fcs_b[0];
#pragma unroll
    for (int q = 0; q < 8; q++) s += partial[(size_t)m * 8 + q];
    out[m] = s;
}

// ---------------------------------------------------------------------------
// Ranks from fp32 scores; flag groups with any pairwise gap < EPS_FLAG.
// ---------------------------------------------------------------------------
__global__ void flag_rank(const float* __restrict__ out_scores,
                          float* __restrict__ out, int* __restrict__ flags) {
    int n = blockIdx.x * 256 + threadIdx.x;
    if (n >= N_BATCH) return;
    float s[5];
#pragma unroll
    for (int i = 0; i < 5; i++) s[i] = out_scores[n * 5 + i];
    int f = 0;
#pragma unroll
    for (int i = 0; i < 5; i++) {
        int rk = 0;
#pragma unroll
        for (int j = 0; j < 5; j++) {
            rk += (s[j] > s[i]) || (s[j] == s[i] && j < i);
            if (j > i) f |= (fabsf(s[i] - s[j]) < EPS_FLAG);
        }
        out[NROWS + n * 5 + i] = (float)rk;
    }
    flags[n] = f;
}

// ---------------------------------------------------------------------------
// Exact f64 recompute of the full chain for flagged samples. One block/sample.
// ---------------------------------------------------------------------------
__global__ __launch_bounds__(256) void recompute_flagged(
    const float* __restrict__ feats,
    const float* __restrict__ w2, const float* __restrict__ b2,
    const float* __restrict__ w3, const float* __restrict__ b3,
    const float* __restrict__ w5, const float* __restrict__ b5,
    const float* __restrict__ fc1_w, const float* __restrict__ fc1_b,
    const float* __restrict__ fc2_w, const float* __restrict__ fc2_b,
    const float* __restrict__ fc0_w, const float* __restrict__ fc0_b,
    const float* __restrict__ fcs_w, const float* __restrict__ fcs_b,
    const int* __restrict__ flags, float* __restrict__ out) {
    int n = blockIdx.x;
    if (!flags[n]) return;
    __shared__ float  fsh[2560];
    __shared__ double csh[600];
    __shared__ double hsh[600];
    __shared__ double cish[512];
    __shared__ double rred[5][4];
    int tid = threadIdx.x, lane = tid & 63, wave = tid >> 6;

    const float4* fg = (const float4*)(feats + (size_t)n * 2560);
    float4* fs4 = (float4*)fsh;
    for (int i = tid; i < 640; i += 256) fs4[i] = fg[i];
    __syncthreads();

    // conv blocks (channels 0..599 across waves; lanes parallel over k*d)
    for (int ch = wave; ch < DCAT; ch += 4) {
        int K, T; const float* w; float b;
        if (ch < 200)      { K = 2; T = 4; w = w2 + (size_t)ch * 1024;          b = b2[ch]; }
        else if (ch < 400) { K = 3; T = 3; w = w3 + (size_t)(ch - 200) * 1536;  b = b3[ch - 200]; }
        else               { K = 5; T = 1; w = w5 + (size_t)(ch - 400) * 2560;  b = b5[ch - 400]; }
        double m = -1e300;
        int kd = K * 512;
        for (int t = 0; t < T; t++) {
            double s = 0.0;
            for (int i = lane; i < kd; i += 64)
                s += (double)fsh[t * 512 + i] * (double)w[i];
#pragma unroll
            for (int o = 32; o >= 1; o >>= 1) s += __shfl_down(s, o, 64);
            m = fmax(m, s + (double)b);
        }
        if (lane == 0) csh[ch] = fmax(m, 0.0);
    }
    __syncthreads();
    // fc1
    for (int ch = wave; ch < DCAT; ch += 4) {
        double s = 0.0;
        for (int k = lane; k < DCAT; k += 64)
            s += csh[k] * (double)fc1_w[(size_t)k * DCAT + ch];
#pragma unroll
        for (int o = 32; o >= 1; o >>= 1) s += __shfl_down(s, o, 64);
        if (lane == 0) hsh[ch] = fmax(s + (double)fc1_b[ch], 0.0);
    }
    __syncthreads();
    // fc2
    for (int ch = wave; ch < DIM; ch += 4) {
        double s = 0.0;
        for (int k = lane; k < DCAT; k += 64)
            s += hsh[k] * (double)fc2_w[(size_t)k * DIM + ch];
#pragma unroll
        for (int o = 32; o >= 1; o >>= 1) s += __shfl_down(s, o, 64);
        if (lane == 0) cish[ch] = s + (double)fc2_b[ch];
    }
    __syncthreads();
    // fc0 + fcs: thread handles cols tid and tid+256
    double acc0[5] = {}, acc1[5] = {};
    for (int k = 0; k < 512; k++) {
        double w0 = (double)fc0_w[(size_t)k * DIM + tid];
        double w1 = (double)fc0_w[(size_t)k * DIM + tid + 256];
#pragma unroll
        for (int img = 0; img < 5; img++) {
            double z = (double)fsh[img * 512 + k];
            acc0[img] += z * w0; acc1[img] += z * w1;
        }
    }
    for (int k = 0; k < 512; k++) {
        double w0 = (double)fc0_w[(size_t)(k + 512) * DIM + tid];
        double w1 = (double)fc0_w[(size_t)(k + 512) * DIM + tid + 256];
        double z = cish[k];
#pragma unroll
        for (int img = 0; img < 5; img++) { acc0[img] += z * w0; acc1[img] += z * w1; }
    }
    double b0a = (double)fc0_b[tid], b0b = (double)fc0_b[tid + 256];
    double fwa = (double)fcs_w[tid], fwb = (double)fcs_w[tid + 256];
#pragma unroll
    for (int img = 0; img < 5; img++) {
        double p = fmax(acc0[img] + b0a, 0.0) * fwa + fmax(acc1[img] + b0b, 0.0) * fwb;
#pragma unroll
        for (int o = 32; o >= 1; o >>= 1) p += __shfl_down(p, o, 64);
        if (lane == 0) rred[img][wave] = p;
    }
    __syncthreads();
    if (tid == 0) {
        double sc[5];
#pragma unroll
        for (int img = 0; img < 5; img++)
            sc[img] = rred[img][0] + rred[img][1] + rred[img][2] + rred[img][3]
                    + (double)fcs_b[0];
#pragma unroll
        for (int i = 0; i < 5; i++) {
            int rk = 0;
#pragma unroll
            for (int j = 0; j < 5; j++)
                rk += (sc[j] > sc[i]) || (sc[j] == sc[i] && j < i);
            out[n * 5 + i] = (float)sc[i];
            out[NROWS + n * 5 + i] = (float)rk;
        }
    }
}

// ---------------------------------------------------------------------------
// Workspace layout (bytes):
//   c [N,600] f32 @ 0          : 78,643,200   (later reused: ci [N,512] f32)
//   reg1 @ 78,643,200          : wT repacks (4.1MB) -> h [N,600] f32 (78.6MB)
//                                -> partial [NROWS,8] f32 (5.24MB)
//   flags @ reg1 + 8,388,608   : 131,072
// ---------------------------------------------------------------------------
extern "C" void kernel_launch(void* const* d_in, const int* in_sizes, int n_in,
                              void* d_out, int out_size, void* d_ws, size_t ws_size,
                              hipStream_t stream) {
    (void)in_sizes; (void)n_in; (void)out_size; (void)ws_size;
    const float* feats = (const float*)d_in[0];
    const float* w2    = (const float*)d_in[1];
    const float* b2    = (const float*)d_in[2];
    const float* w3    = (const float*)d_in[3];
    const float* b3    = (const float*)d_in[4];
    const float* w5    = (const float*)d_in[5];
    const float* b5    = (const float*)d_in[6];
    const float* fc1_w = (const float*)d_in[7];
    const float* fc1_b = (const float*)d_in[8];
    const float* fc2_w = (const float*)d_in[9];
    const float* fc2_b = (const float*)d_in[10];
    const float* fc0_w = (const float*)d_in[11];
    const float* fc0_b = (const float*)d_in[12];
    const float* fcs_w = (const float*)d_in[13];
    const float* fcs_b = (const float*)d_in[14];

    char* ws = (char*)d_ws;
    float* c    = (float*)ws;
    float* reg1 = (float*)(ws + 78643200);
    float* w2T = reg1;
    float* w3T = reg1 + 204800;
    float* w5T = reg1 + 512000;
    int* flags = (int*)(ws + 78643200 + 8388608);

    transpose_w<2><<<dim3((2 * 128 * NKERN + 255) / 256), 256, 0, stream>>>(w2, w2T);
    transpose_w<3><<<dim3((3 * 128 * NKERN + 255) / 256), 256, 0, stream>>>(w3, w3T);
    transpose_w<5><<<dim3((5 * 128 * NKERN + 255) / 256), 256, 0, stream>>>(w5, w5T);

    conv_relu_max<2, 4><<<dim3(N_BATCH / 4, 2), 256, 0, stream>>>(feats, w2T, b2, c, 0);
    conv_relu_max<3, 3><<<dim3(N_BATCH / 4, 2), 256, 0, stream>>>(feats, w3T, b3, c, 200);
    conv_relu_max<5, 1><<<dim3(N_BATCH / 4, 2), 256, 0, stream>>>(feats, w5T, b5, c, 400);

    float* h = reg1;                               // overwrites wT (dead)
    gemm_bias<1><<<dim3(N_BATCH / 64, 10), 256, 0, stream>>>(c, fc1_w, fc1_b, h, DCAT, DCAT);

    float* ci = (float*)ws;                        // overwrites c (dead)
    gemm_bias<0><<<dim3(N_BATCH / 64, 8), 256, 0, stream>>>(h, fc2_w, fc2_b, ci, DCAT, DIM);

    float* partial = reg1;                         // overwrites h (dead)
    fc0_fcs_partial<<<dim3(NROWS / 64, 8), 256, 0, stream>>>(feats, ci, fc0_w, fc0_b, fcs_w, partial);

    float* out = (float*)d_out;
    score_finish<<<dim3((NROWS + 255) / 256), 256, 0, stream>>>(partial, fcs_b, out);
    flag_rank<<<dim3((N_BATCH + 255) / 256), 256, 0, stream>>>(out, out, flags);
    recompute_flagged<<<dim3(N_BATCH), 256, 0, stream>>>(
        feats, w2, b2, w3, b3, w5, b5, fc1_w, fc1_b, fc2_w, fc2_b,
        fc0_w, fc0_b, fcs_w, fcs_b, flags, out);
}